// Round 1
// baseline (245.676 us; speedup 1.0000x reference)
//
#include <hip/hip_runtime.h>

#define F_IN 16
#define F_EDGE 8
#define H 8

// out[g] = blast (pool kernel accumulates on top)
__global__ void init_out_kernel(float* __restrict__ out,
                                const float* __restrict__ blast, int n) {
    int g = blockIdx.x * blockDim.x + threadIdx.x;
    if (g < n) out[g] = blast[0];
}

// h1pre[n][j] = b1[j] + sum_i x[n][i] * root1[i][j]
__global__ void node_root1_kernel(const float* __restrict__ x,
                                  const float* __restrict__ root1,
                                  const float* __restrict__ b1,
                                  float* __restrict__ h1pre, int n_nodes) {
    int idx = blockIdx.x * blockDim.x + threadIdx.x;
    if (idx >= n_nodes * H) return;
    int n = idx >> 3, j = idx & 7;
    float acc = b1[j];
#pragma unroll
    for (int i = 0; i < F_IN; ++i)
        acc = fmaf(x[n * F_IN + i], root1[i * H + j], acc);
    h1pre[idx] = acc;
}

// Edge kernel: 8 lanes per edge; lane j computes output feature j.
// msg_j = sum_i feat[src][i] * (be[i*8+j] + sum_k ea[k] * We[k][i*8+j])
// then atomicAdd into agg[dst*8+j].
template <int IN>
__global__ void edge_kernel(const int* __restrict__ ei,   // [2, E]
                            const float* __restrict__ ea, // [E, 8]
                            const float* __restrict__ feat,
                            const float* __restrict__ We, // [8, IN*8]
                            const float* __restrict__ be, // [IN*8]
                            float* __restrict__ agg, int E) {
    constexpr int WSZ = F_EDGE * IN * H;
    __shared__ float sW[WSZ];
    __shared__ float sb[IN * H];
    for (int t = threadIdx.x; t < WSZ; t += blockDim.x) sW[t] = We[t];
    for (int t = threadIdx.x; t < IN * H; t += blockDim.x) sb[t] = be[t];
    __syncthreads();

    long long gid = (long long)blockIdx.x * blockDim.x + threadIdx.x;
    int e = (int)(gid >> 3);
    if (e >= E) return;
    int j = (int)(gid & 7);

    int src = ei[e];
    int dst = ei[E + e];

    float a[F_EDGE];
#pragma unroll
    for (int k = 0; k < F_EDGE; ++k) a[k] = ea[(long long)e * F_EDGE + k];

    float m = 0.f;
#pragma unroll
    for (int i = 0; i < IN; ++i) {
        float w = sb[i * H + j];
#pragma unroll
        for (int k = 0; k < F_EDGE; ++k)
            w = fmaf(a[k], sW[k * (IN * H) + i * H + j], w);
        m = fmaf(feat[(long long)src * IN + i], w, m);
    }
    unsafeAtomicAdd(&agg[(long long)dst * H + j], m);
}

// h1[n][j] = relu(h1pre[n][j]); h2pre[n][j] = b2[j] + sum_i h1[n][i]*root2[i][j]
__global__ void relu_root2_kernel(const float* __restrict__ h1pre,
                                  const float* __restrict__ root2,
                                  const float* __restrict__ b2,
                                  float* __restrict__ h1,
                                  float* __restrict__ h2pre, int n_nodes) {
    int idx = blockIdx.x * blockDim.x + threadIdx.x;
    if (idx >= n_nodes * H) return;
    int n = idx >> 3, j = idx & 7;
    float acc = b2[j];
#pragma unroll
    for (int i = 0; i < H; ++i) {
        float hv = h1pre[n * H + i];
        hv = hv > 0.f ? hv : 0.f;
        acc = fmaf(hv, root2[i * H + j], acc);
    }
    float own = h1pre[idx];
    h1[idx] = own > 0.f ? own : 0.f;
    h2pre[idx] = acc;
}

// per node: relu(h2pre[n]) . Wlast -> atomicAdd out[batch[n]]
__global__ void pool_kernel(const float* __restrict__ h2pre,
                            const int* __restrict__ batch,
                            const float* __restrict__ Wlast,
                            float* __restrict__ out, int n_nodes) {
    int n = blockIdx.x * blockDim.x + threadIdx.x;
    if (n >= n_nodes) return;
    float c = 0.f;
#pragma unroll
    for (int j = 0; j < H; ++j) {
        float hv = h2pre[n * H + j];
        hv = hv > 0.f ? hv : 0.f;
        c = fmaf(hv, Wlast[j], c);
    }
    unsafeAtomicAdd(&out[batch[n]], c);
}

extern "C" void kernel_launch(void* const* d_in, const int* in_sizes, int n_in,
                              void* d_out, int out_size, void* d_ws, size_t ws_size,
                              hipStream_t stream) {
    const float* x     = (const float*)d_in[0];
    const int*   ei    = (const int*)d_in[1];
    const float* ea    = (const float*)d_in[2];
    const int*   batch = (const int*)d_in[3];
    const float* We1   = (const float*)d_in[4];
    const float* be1   = (const float*)d_in[5];
    const float* root1 = (const float*)d_in[6];
    const float* b1    = (const float*)d_in[7];
    const float* We2   = (const float*)d_in[8];
    const float* be2   = (const float*)d_in[9];
    const float* root2 = (const float*)d_in[10];
    const float* b2    = (const float*)d_in[11];
    const float* Wlast = (const float*)d_in[12];
    const float* blast = (const float*)d_in[13];
    float* out = (float*)d_out;

    int n_nodes = in_sizes[0] / F_IN;
    int E = in_sizes[1] / 2;

    float* h1pre = (float*)d_ws;
    float* h1    = h1pre + (size_t)n_nodes * H;
    float* h2pre = h1 + (size_t)n_nodes * H;

    init_out_kernel<<<(out_size + 255) / 256, 256, 0, stream>>>(out, blast, out_size);

    int nj = n_nodes * H;
    node_root1_kernel<<<(nj + 255) / 256, 256, 0, stream>>>(x, root1, b1, h1pre, n_nodes);

    long long lanes = (long long)E * H;
    int eblks = (int)((lanes + 255) / 256);
    edge_kernel<F_IN><<<eblks, 256, 0, stream>>>(ei, ea, x, We1, be1, h1pre, E);

    relu_root2_kernel<<<(nj + 255) / 256, 256, 0, stream>>>(h1pre, root2, b2, h1, h2pre, n_nodes);

    edge_kernel<H><<<eblks, 256, 0, stream>>>(ei, ea, h1, We2, be2, h2pre, E);

    pool_kernel<<<(n_nodes + 255) / 256, 256, 0, stream>>>(h2pre, batch, Wlast, out, n_nodes);
}

// Round 2
// 242.018 us; speedup vs baseline: 1.0151x; 1.0151x over previous
//
#include <hip/hip_runtime.h>

#define F_IN 16
#define F_EDGE 8
#define H 8

// out[g] = blast (pool kernel accumulates on top)
__global__ void init_out_kernel(float* __restrict__ out,
                                const float* __restrict__ blast, int n) {
    int g = blockIdx.x * blockDim.x + threadIdx.x;
    if (g < n) out[g] = blast[0];
}

// Per-node precompute for one NNConv layer, factorized:
//   Pt[n][j][k]   = sum_i feat[n][i] * We[k][i*H+j]       (k=0..7)
//   q[n][j]       = sum_i feat[n][i] * be[i*H+j]
//   aggseed[n][j] = b[j] + sum_i feat[n][i] * root[i*H+j]
// feat is optionally relu'd on load (layer 2 reads pre-activation h1pre).
// One thread per (n, j); 32 nodes per 256-thread block.
template <int IN, bool RELU>
__global__ __launch_bounds__(256) void prep_kernel(
    const float* __restrict__ feat,  // [n_nodes, IN]
    const float* __restrict__ We,    // [F_EDGE, IN*H]
    const float* __restrict__ be,    // [IN*H]
    const float* __restrict__ root,  // [IN, H]
    const float* __restrict__ b,     // [H]
    float* __restrict__ Pt,          // [n_nodes, H, F_EDGE]
    float* __restrict__ q,           // [n_nodes, H]
    float* __restrict__ aggseed,     // [n_nodes, H]
    int n_nodes) {
    __shared__ float sWe[F_EDGE * IN * H];
    __shared__ float sbe[IN * H];
    __shared__ float sroot[IN * H];
    __shared__ float sf[32 * IN];

    int tid = threadIdx.x;
    for (int t = tid; t < F_EDGE * IN * H; t += 256) sWe[t] = We[t];
    for (int t = tid; t < IN * H; t += 256) {
        sbe[t] = be[t];
        sroot[t] = root[t];
    }
    int n0 = blockIdx.x * 32;
    for (int t = tid; t < 32 * IN; t += 256) {
        long long g = (long long)n0 * IN + t;
        float v = (g < (long long)n_nodes * IN) ? feat[g] : 0.f;
        if (RELU) v = v > 0.f ? v : 0.f;
        sf[t] = v;
    }
    __syncthreads();

    int n = n0 + (tid >> 3);
    int j = tid & 7;
    if (n >= n_nodes) return;

    const float* fr = &sf[(tid >> 3) * IN];
    float p[F_EDGE] = {0.f, 0.f, 0.f, 0.f, 0.f, 0.f, 0.f, 0.f};
    float qq = 0.f, hr = 0.f;
#pragma unroll
    for (int i = 0; i < IN; ++i) {
        float fi = fr[i];
#pragma unroll
        for (int k = 0; k < F_EDGE; ++k)
            p[k] = fmaf(fi, sWe[k * (IN * H) + i * H + j], p[k]);
        qq = fmaf(fi, sbe[i * H + j], qq);
        hr = fmaf(fi, sroot[i * H + j], hr);
    }
    long long base = ((long long)n * H + j) * F_EDGE;
    float4* pv = (float4*)(Pt + base);
    pv[0] = make_float4(p[0], p[1], p[2], p[3]);
    pv[1] = make_float4(p[4], p[5], p[6], p[7]);
    q[(long long)n * H + j] = qq;
    aggseed[(long long)n * H + j] = hr + b[j];
}

// Factorized edge kernel (shared by both layers):
//   msg_j = q[src][j] + sum_k ea[e][k] * Pt[src][j][k]
//   atomicAdd(agg[dst][j], msg_j)
// 8 lanes per edge (lane j = output feature j).
__global__ __launch_bounds__(256) void edge_fact_kernel(
    const int* __restrict__ ei,   // [2, E]
    const float* __restrict__ ea, // [E, F_EDGE]
    const float* __restrict__ Pt, // [n_nodes, H, F_EDGE]
    const float* __restrict__ q,  // [n_nodes, H]
    float* __restrict__ agg,      // [n_nodes, H]
    int E) {
    long long gid = (long long)blockIdx.x * blockDim.x + threadIdx.x;
    int e = (int)(gid >> 3);
    if (e >= E) return;
    int j = (int)(gid & 7);

    int src = ei[e];
    int dst = ei[E + e];

    const float4* av = (const float4*)(ea + (long long)e * F_EDGE);
    float4 a0 = av[0], a1 = av[1];

    const float4* pv = (const float4*)(Pt + ((long long)src * H + j) * F_EDGE);
    float4 p0 = pv[0], p1 = pv[1];

    float m = q[(long long)src * H + j];
    m = fmaf(a0.x, p0.x, m);
    m = fmaf(a0.y, p0.y, m);
    m = fmaf(a0.z, p0.z, m);
    m = fmaf(a0.w, p0.w, m);
    m = fmaf(a1.x, p1.x, m);
    m = fmaf(a1.y, p1.y, m);
    m = fmaf(a1.z, p1.z, m);
    m = fmaf(a1.w, p1.w, m);

    unsafeAtomicAdd(&agg[(long long)dst * H + j], m);
}

// per node: relu(h2pre[n]) . Wlast -> atomicAdd out[batch[n]]
__global__ void pool_kernel(const float* __restrict__ h2pre,
                            const int* __restrict__ batch,
                            const float* __restrict__ Wlast,
                            float* __restrict__ out, int n_nodes) {
    int n = blockIdx.x * blockDim.x + threadIdx.x;
    if (n >= n_nodes) return;
    float c = 0.f;
#pragma unroll
    for (int j = 0; j < H; ++j) {
        float hv = h2pre[(long long)n * H + j];
        hv = hv > 0.f ? hv : 0.f;
        c = fmaf(hv, Wlast[j], c);
    }
    unsafeAtomicAdd(&out[batch[n]], c);
}

extern "C" void kernel_launch(void* const* d_in, const int* in_sizes, int n_in,
                              void* d_out, int out_size, void* d_ws, size_t ws_size,
                              hipStream_t stream) {
    const float* x     = (const float*)d_in[0];
    const int*   ei    = (const int*)d_in[1];
    const float* ea    = (const float*)d_in[2];
    const int*   batch = (const int*)d_in[3];
    const float* We1   = (const float*)d_in[4];
    const float* be1   = (const float*)d_in[5];
    const float* root1 = (const float*)d_in[6];
    const float* b1    = (const float*)d_in[7];
    const float* We2   = (const float*)d_in[8];
    const float* be2   = (const float*)d_in[9];
    const float* root2 = (const float*)d_in[10];
    const float* b2    = (const float*)d_in[11];
    const float* Wlast = (const float*)d_in[12];
    const float* blast = (const float*)d_in[13];
    float* out = (float*)d_out;

    int n_nodes = in_sizes[0] / F_IN;
    int E = in_sizes[1] / 2;

    size_t nH = (size_t)n_nodes * H;
    float* Pt1   = (float*)d_ws;            // n*64
    float* q1    = Pt1 + (size_t)n_nodes * H * F_EDGE;
    float* h1pre = q1 + nH;
    float* Pt2   = h1pre + nH;
    float* q2    = Pt2 + (size_t)n_nodes * H * F_EDGE;
    float* h2pre = q2 + nH;

    init_out_kernel<<<(out_size + 255) / 256, 256, 0, stream>>>(out, blast, out_size);

    int nblocks = (n_nodes + 31) / 32;
    prep_kernel<F_IN, false><<<nblocks, 256, 0, stream>>>(
        x, We1, be1, root1, b1, Pt1, q1, h1pre, n_nodes);

    long long lanes = (long long)E * H;
    int eblks = (int)((lanes + 255) / 256);
    edge_fact_kernel<<<eblks, 256, 0, stream>>>(ei, ea, Pt1, q1, h1pre, E);

    prep_kernel<H, true><<<nblocks, 256, 0, stream>>>(
        h1pre, We2, be2, root2, b2, Pt2, q2, h2pre, n_nodes);

    edge_fact_kernel<<<eblks, 256, 0, stream>>>(ei, ea, Pt2, q2, h2pre, E);

    pool_kernel<<<(n_nodes + 255) / 256, 256, 0, stream>>>(h2pre, batch, Wlast, out, n_nodes);
}

// Round 3
// 197.578 us; speedup vs baseline: 1.2434x; 1.2249x over previous
//
#include <hip/hip_runtime.h>

#define F_EDGE 8
#define H 8

__device__ __forceinline__ unsigned short f2bf(float f) {
    unsigned u = __float_as_uint(f);
    unsigned r = u + 0x7fffu + ((u >> 16) & 1u);
    return (unsigned short)(r >> 16);
}
__device__ __forceinline__ float bflo(unsigned u) { return __uint_as_float(u << 16); }
__device__ __forceinline__ float bfhi(unsigned u) { return __uint_as_float(u & 0xffff0000u); }

// out[g] = blast (pool kernel accumulates on top)
__global__ void init_out_kernel(float* __restrict__ out,
                                const float* __restrict__ blast, int n) {
    int g = blockIdx.x * blockDim.x + threadIdx.x;
    if (g < n) out[g] = blast[0];
}

// Per-node precompute for one NNConv layer, factorized:
//   Pt[n][j][k]   = sum_i feat[n][i] * We[k][i*H+j]   (stored bf16)
//   q[n][j]       = sum_i feat[n][i] * be[i*H+j]
//   aggseed[n][j] = b[j] + sum_i feat[n][i] * root[i*H+j]
// LDS holds a fused weight row per (i,j): [We k=0..7 | be | root | pad pad]
// so the inner loop is 2x ds_read_b128 + 1x ds_read_b64 per i (was 10x b32).
template <int IN, bool RELU>
__global__ __launch_bounds__(256) void prep_kernel(
    const float* __restrict__ feat,       // [n_nodes, IN]
    const float* __restrict__ We,         // [F_EDGE, IN*H]
    const float* __restrict__ be,         // [IN*H]
    const float* __restrict__ root,       // [IN, H]
    const float* __restrict__ b,          // [H]
    unsigned short* __restrict__ Pt,      // [n_nodes, H, F_EDGE] bf16
    float* __restrict__ q,                // [n_nodes, H]
    float* __restrict__ aggseed,          // [n_nodes, H]
    int n_nodes) {
    __shared__ float sW[IN * H * 12];
    int tid = threadIdx.x;
    for (int t = tid; t < IN * H * 12; t += 256) {
        int r = t / 12, m = t - r * 12;   // r = i*H + j
        float v = 0.f;
        if (m < 8) v = We[m * (IN * H) + r];
        else if (m == 8) v = be[r];
        else if (m == 9) v = root[r];
        sW[t] = v;
    }
    __syncthreads();

    int n = blockIdx.x * 32 + (tid >> 3);
    if (n >= n_nodes) return;
    int j = tid & 7;

    float f[IN];
    const float4* fv = (const float4*)(feat + (long long)n * IN);
#pragma unroll
    for (int i4 = 0; i4 < IN / 4; ++i4) {
        float4 v = fv[i4];
        f[i4 * 4 + 0] = v.x; f[i4 * 4 + 1] = v.y;
        f[i4 * 4 + 2] = v.z; f[i4 * 4 + 3] = v.w;
    }
    if (RELU) {
#pragma unroll
        for (int i = 0; i < IN; ++i) f[i] = f[i] > 0.f ? f[i] : 0.f;
    }

    float p[8] = {0.f, 0.f, 0.f, 0.f, 0.f, 0.f, 0.f, 0.f};
    float qq = 0.f, hr = 0.f;
#pragma unroll
    for (int i = 0; i < IN; ++i) {
        const float* row = &sW[(i * 8 + j) * 12];
        float4 w0 = *(const float4*)row;
        float4 w1 = *(const float4*)(row + 4);
        float2 br = *(const float2*)(row + 8);
        float fi = f[i];
        p[0] = fmaf(fi, w0.x, p[0]); p[1] = fmaf(fi, w0.y, p[1]);
        p[2] = fmaf(fi, w0.z, p[2]); p[3] = fmaf(fi, w0.w, p[3]);
        p[4] = fmaf(fi, w1.x, p[4]); p[5] = fmaf(fi, w1.y, p[5]);
        p[6] = fmaf(fi, w1.z, p[6]); p[7] = fmaf(fi, w1.w, p[7]);
        qq = fmaf(fi, br.x, qq);
        hr = fmaf(fi, br.y, hr);
    }
    uint4 pw;
    pw.x = (unsigned)f2bf(p[0]) | ((unsigned)f2bf(p[1]) << 16);
    pw.y = (unsigned)f2bf(p[2]) | ((unsigned)f2bf(p[3]) << 16);
    pw.z = (unsigned)f2bf(p[4]) | ((unsigned)f2bf(p[5]) << 16);
    pw.w = (unsigned)f2bf(p[6]) | ((unsigned)f2bf(p[7]) << 16);
    *(uint4*)(Pt + ((long long)n * H + j) * F_EDGE) = pw;
    q[(long long)n * H + j] = qq;
    aggseed[(long long)n * H + j] = hr + b[j];
}

// Factorized edge kernel (both layers):
//   msg_j = q[src][j] + sum_k ea[e][k] * Pt_bf16[src][j][k]
//   atomicAdd(agg[dst][j], msg_j)
// 8 lanes per edge; Pt row per lane is ONE 16B load (one cache line/edge).
__global__ __launch_bounds__(256) void edge_fact_kernel(
    const int* __restrict__ ei,             // [2, E]
    const float* __restrict__ ea,           // [E, F_EDGE]
    const unsigned short* __restrict__ Pt,  // [n_nodes, H, F_EDGE] bf16
    const float* __restrict__ q,            // [n_nodes, H]
    float* __restrict__ agg,                // [n_nodes, H]
    int E) {
    long long gid = (long long)blockIdx.x * blockDim.x + threadIdx.x;
    int e = (int)(gid >> 3);
    if (e >= E) return;
    int j = (int)(gid & 7);

    int src = ei[e];
    int dst = ei[E + e];

    const float4* av = (const float4*)(ea + (long long)e * F_EDGE);
    float4 a0 = av[0], a1 = av[1];

    uint4 pw = *(const uint4*)(Pt + ((long long)src * H + j) * F_EDGE);

    float m = q[(long long)src * H + j];
    m = fmaf(a0.x, bflo(pw.x), m);
    m = fmaf(a0.y, bfhi(pw.x), m);
    m = fmaf(a0.z, bflo(pw.y), m);
    m = fmaf(a0.w, bfhi(pw.y), m);
    m = fmaf(a1.x, bflo(pw.z), m);
    m = fmaf(a1.y, bfhi(pw.z), m);
    m = fmaf(a1.z, bflo(pw.w), m);
    m = fmaf(a1.w, bfhi(pw.w), m);

    unsafeAtomicAdd(&agg[(long long)dst * H + j], m);
}

// Pool: per-block LDS bins (batch is sorted -> few hot bins per block),
// then one global atomic per nonzero bin.
__global__ __launch_bounds__(256) void pool_kernel(
    const float* __restrict__ h2pre, const int* __restrict__ batch,
    const float* __restrict__ Wlast, float* __restrict__ out,
    int n_nodes, int n_graphs) {
    __shared__ float bins[512];
    bool use_bins = (n_graphs <= 512);
    if (use_bins) {
        for (int t = threadIdx.x; t < n_graphs; t += 256) bins[t] = 0.f;
        __syncthreads();
    }
    float wl[8];
#pragma unroll
    for (int j = 0; j < 8; ++j) wl[j] = Wlast[j];

    int base = blockIdx.x * 1024;
#pragma unroll
    for (int r = 0; r < 4; ++r) {
        int n = base + r * 256 + threadIdx.x;
        if (n < n_nodes) {
            const float4* hv = (const float4*)(h2pre + (long long)n * H);
            float4 h0 = hv[0], h1 = hv[1];
            float c = 0.f;
            c = fmaf(fmaxf(h0.x, 0.f), wl[0], c);
            c = fmaf(fmaxf(h0.y, 0.f), wl[1], c);
            c = fmaf(fmaxf(h0.z, 0.f), wl[2], c);
            c = fmaf(fmaxf(h0.w, 0.f), wl[3], c);
            c = fmaf(fmaxf(h1.x, 0.f), wl[4], c);
            c = fmaf(fmaxf(h1.y, 0.f), wl[5], c);
            c = fmaf(fmaxf(h1.z, 0.f), wl[6], c);
            c = fmaf(fmaxf(h1.w, 0.f), wl[7], c);
            if (use_bins) atomicAdd(&bins[batch[n]], c);
            else unsafeAtomicAdd(&out[batch[n]], c);
        }
    }
    if (use_bins) {
        __syncthreads();
        for (int t = threadIdx.x; t < n_graphs; t += 256) {
            float v = bins[t];
            if (v != 0.f) unsafeAtomicAdd(&out[t], v);
        }
    }
}

extern "C" void kernel_launch(void* const* d_in, const int* in_sizes, int n_in,
                              void* d_out, int out_size, void* d_ws, size_t ws_size,
                              hipStream_t stream) {
    const float* x     = (const float*)d_in[0];
    const int*   ei    = (const int*)d_in[1];
    const float* ea    = (const float*)d_in[2];
    const int*   batch = (const int*)d_in[3];
    const float* We1   = (const float*)d_in[4];
    const float* be1   = (const float*)d_in[5];
    const float* root1 = (const float*)d_in[6];
    const float* b1    = (const float*)d_in[7];
    const float* We2   = (const float*)d_in[8];
    const float* be2   = (const float*)d_in[9];
    const float* root2 = (const float*)d_in[10];
    const float* b2    = (const float*)d_in[11];
    const float* Wlast = (const float*)d_in[12];
    const float* blast = (const float*)d_in[13];
    float* out = (float*)d_out;

    int F_IN_rt = 16;
    int n_nodes = in_sizes[0] / F_IN_rt;
    int E = in_sizes[1] / 2;

    size_t nH = (size_t)n_nodes * H;
    unsigned short* Pt1 = (unsigned short*)d_ws;          // n*64 bf16
    unsigned short* Pt2 = Pt1 + (size_t)n_nodes * H * F_EDGE;
    float* q1    = (float*)(Pt2 + (size_t)n_nodes * H * F_EDGE);
    float* q2    = q1 + nH;
    float* h1pre = q2 + nH;
    float* h2pre = h1pre + nH;

    init_out_kernel<<<(out_size + 255) / 256, 256, 0, stream>>>(out, blast, out_size);

    int nblocks = (n_nodes + 31) / 32;
    prep_kernel<16, false><<<nblocks, 256, 0, stream>>>(
        x, We1, be1, root1, b1, Pt1, q1, h1pre, n_nodes);

    long long lanes = (long long)E * H;
    int eblks = (int)((lanes + 255) / 256);
    edge_fact_kernel<<<eblks, 256, 0, stream>>>(ei, ea, Pt1, q1, h1pre, E);

    prep_kernel<H, true><<<nblocks, 256, 0, stream>>>(
        h1pre, We2, be2, root2, b2, Pt2, q2, h2pre, n_nodes);

    edge_fact_kernel<<<eblks, 256, 0, stream>>>(ei, ea, Pt2, q2, h2pre, E);

    int pblocks = (n_nodes + 1023) / 1024;
    pool_kernel<<<pblocks, 256, 0, stream>>>(h2pre, batch, Wlast, out, n_nodes, out_size);
}